// Round 11
// baseline (41.185 us; speedup 1.0000x reference)
//
#include <hip/hip_runtime.h>

#define BB 16
#define QQ 200
#define NN 200
#define CC 64
#define TT 100
#define GG 50
#define SS 4
#define EE (GG*SS)   // 200

// Fused kernel, full-slab sweep variant: one block per (b,q).
//  - stats loop sweeps ALL 200 rows sequentially (no index indirection,
//    perfectly coalesced 1KB wave-loads, fixed-trip predicated unroll)
//  - sort runs before stats but loads don't depend on it
//  - gather looks up sm_sh by row id; group-of-4 sum; broadcast write.
__global__ __launch_bounds__(256) void edge_cost_fused_kernel(
    const float* __restrict__ edges,          // [B,Q,N,C]
    const int* __restrict__ query_indices,    // [B,T]
    const int* __restrict__ target_indices,   // [B,T]
    const int* __restrict__ col_ids,          // [B,E]
    const int* __restrict__ edge_tgt,         // [B,E]
    float* __restrict__ out)                  // [B,Q,B*G]
{
    const int blk = blockIdx.x;
    const int b = blk / QQ;
    const int q = blk % QQ;
    const int tid = threadIdx.x;

    __shared__ int   tk[TT];
    __shared__ int   qi[TT];
    __shared__ int   sq_sh[TT];
    __shared__ int   ep_sh[EE];     // t*64 + class packed
    __shared__ float sm_sh[NN];     // sum-exp per ROW id (all 200 rows)
    __shared__ float cost_sh[GG];

    if (tid < TT) {
        tk[tid] = target_indices[b * TT + tid];
        qi[tid] = query_indices[b * TT + tid];
    }
    if (tid < EE) {
        const int t_e = col_ids[b * EE + tid];
        const int c_e = edge_tgt[b * EE + tid];
        ep_sh[tid] = t_e * 64 + c_e;
    }

    const float* base = edges + ((size_t)(b * QQ + q)) * NN * CC;

    // Stats: sum-exp for ALL rows; 16 groups x 16 lanes; each wave-load is
    // 1KB contiguous (4 consecutive rows). 13 predicated iterations, fully
    // unrolled -> all loads in flight, zero dependence on the sort.
    const int grp  = tid >> 4;
    const int lane = tid & 15;
    #pragma unroll
    for (int it = 0; it < 13; ++it) {
        const int n = grp + it * 16;
        if (n < NN) {
            const float4 v = reinterpret_cast<const float4*>(base + (size_t)n * CC)[lane];
            float e = __expf(v.x) + __expf(v.y) + __expf(v.z) + __expf(v.w);
            #pragma unroll
            for (int off = 1; off < 16; off <<= 1)
                e += __shfl_xor(e, off, 64);
            if (lane == 0) sm_sh[n] = e;
        }
    }

    __syncthreads();

    // Stable argsort by rank (ties broken by original index).
    if (tid < TT) {
        const int key = tk[tid];
        int rank = 0;
        #pragma unroll 4
        for (int j = 0; j < TT; ++j) {
            const int kj = tk[j];
            rank += (kj < key) || (kj == key && j < tid);
        }
        sq_sh[rank] = qi[tid];
    }
    __syncthreads();

    // Gather: per-edge probability, group-of-4 reduce.
    if (tid < EE) {
        const int pack = ep_sh[tid];
        const int t_e = pack >> 6;
        const int c   = pack & 63;
        const int n_e = sq_sh[t_e];
        const float x = base[(size_t)n_e * CC + c];
        float p = __expf(x) / sm_sh[n_e];
        p += __shfl_xor(p, 1, 64);
        p += __shfl_xor(p, 2, 64);
        if ((tid & 3) == 0) cost_sh[tid >> 2] = -p;
    }
    __syncthreads();

    // Broadcast write: out[b2, q, b*G+g] for all b2.
    for (int i = tid; i < BB * GG; i += 256) {
        const int b2 = i / GG;
        const int g  = i % GG;
        out[((size_t)b2 * QQ + q) * (BB * GG) + b * GG + g] = cost_sh[g];
    }
}

extern "C" void kernel_launch(void* const* d_in, const int* in_sizes, int n_in,
                              void* d_out, int out_size, void* d_ws, size_t ws_size,
                              hipStream_t stream) {
    const float* edges = (const float*)d_in[0];          // [B,Q,N,C] f32
    const int* query_indices  = (const int*)d_in[1];     // [B,T]
    const int* target_indices = (const int*)d_in[2];     // [B,T]
    const int* col_ids        = (const int*)d_in[3];     // [B,G,S]
    const int* edge_tgt       = (const int*)d_in[4];     // [B,G,S]
    float* out = (float*)d_out;                          // [B,Q,B*G]

    edge_cost_fused_kernel<<<BB * QQ, 256, 0, stream>>>(
        edges, query_indices, target_indices, col_ids, edge_tgt, out);
}

// Round 12
// 25.943 us; speedup vs baseline: 1.5875x; 1.5875x over previous
//
#include <hip/hip_runtime.h>

#define BB 16
#define QQ 200
#define NN 200
#define CC 64
#define TT 100
#define GG 50
#define SS 4
#define EE (GG*SS)   // 200
#define QPB 2        // q's per block; all loop bounds stay compile-time

// Fused kernel, 2 q's per block: one block per (b, q-pair).
//  - sort + index staging once per block, amortized over 2 q-slabs
//  - stats loop: compile-time bound, fully unrolled, loads BOTH slabs per
//    iteration (2x load ILP; no runtime trip counts anywhere)
//  - per-edge gather for both q's; group-of-4 sum; broadcast write.
__global__ __launch_bounds__(256) void edge_cost_fused_kernel(
    const float* __restrict__ edges,          // [B,Q,N,C]
    const int* __restrict__ query_indices,    // [B,T]
    const int* __restrict__ target_indices,   // [B,T]
    const int* __restrict__ col_ids,          // [B,E]
    const int* __restrict__ edge_tgt,         // [B,E]
    float* __restrict__ out)                  // [B,Q,B*G]
{
    const int blk = blockIdx.x;
    const int b  = blk / (QQ / QPB);
    const int q0 = (blk % (QQ / QPB)) * QPB;
    const int tid = threadIdx.x;

    __shared__ int   tk[TT];
    __shared__ int   qi[TT];
    __shared__ int   sq_sh[TT];
    __shared__ int   ep_sh[EE];          // t*64 + class packed
    __shared__ float sm_sh[QPB][TT];
    __shared__ float cost_sh[QPB][GG];

    if (tid < TT) {
        tk[tid] = target_indices[b * TT + tid];
        qi[tid] = query_indices[b * TT + tid];
    }
    if (tid < EE) {
        const int t_e = col_ids[b * EE + tid];
        const int c_e = edge_tgt[b * EE + tid];
        ep_sh[tid] = t_e * 64 + c_e;
    }
    __syncthreads();

    // Stable argsort by rank (ties broken by original index).
    if (tid < TT) {
        const int key = tk[tid];
        int rank = 0;
        #pragma unroll 4
        for (int j = 0; j < TT; ++j) {
            const int kj = tk[j];
            rank += (kj < key) || (kj == key && j < tid);
        }
        sq_sh[rank] = qi[tid];
    }
    __syncthreads();

    const float* base = edges + ((size_t)(b * QQ + q0)) * NN * CC;

    // Stats: sum-exp per referenced row, both slabs per iteration.
    // Compile-time bound -> full unroll, all loads pipelined.
    const int grp  = tid >> 4;
    const int lane = tid & 15;
    #pragma unroll
    for (int t = grp; t < TT; t += 16) {
        const float* r0 = base + (size_t)sq_sh[t] * CC;
        const float4 v0 = reinterpret_cast<const float4*>(r0)[lane];
        const float4 v1 = reinterpret_cast<const float4*>(r0 + NN * CC)[lane];
        float e0 = __expf(v0.x) + __expf(v0.y) + __expf(v0.z) + __expf(v0.w);
        float e1 = __expf(v1.x) + __expf(v1.y) + __expf(v1.z) + __expf(v1.w);
        #pragma unroll
        for (int off = 1; off < 16; off <<= 1) {
            e0 += __shfl_xor(e0, off, 64);
            e1 += __shfl_xor(e1, off, 64);
        }
        if (lane == 0) { sm_sh[0][t] = e0; sm_sh[1][t] = e1; }
    }
    __syncthreads();

    // Gather: per-edge probability for both q's, group-of-4 reduce.
    if (tid < EE) {
        const int pack = ep_sh[tid];
        const int t_e = pack >> 6;
        const int c   = pack & 63;
        const size_t roff = (size_t)sq_sh[t_e] * CC + c;
        const float x0 = base[roff];
        const float x1 = base[(size_t)NN * CC + roff];
        float p0 = __expf(x0) / sm_sh[0][t_e];
        float p1 = __expf(x1) / sm_sh[1][t_e];
        p0 += __shfl_xor(p0, 1, 64);  p1 += __shfl_xor(p1, 1, 64);
        p0 += __shfl_xor(p0, 2, 64);  p1 += __shfl_xor(p1, 2, 64);
        if ((tid & 3) == 0) {
            cost_sh[0][tid >> 2] = -p0;
            cost_sh[1][tid >> 2] = -p1;
        }
    }
    __syncthreads();

    // Broadcast write: out[b2, q0+qq, b*G+g] for all b2, both q's.
    for (int i = tid; i < QPB * BB * GG; i += 256) {
        const int qq = i / (BB * GG);
        const int r  = i % (BB * GG);
        const int b2 = r / GG;
        const int g  = r % GG;
        out[((size_t)b2 * QQ + q0 + qq) * (BB * GG) + b * GG + g] = cost_sh[qq][g];
    }
}

extern "C" void kernel_launch(void* const* d_in, const int* in_sizes, int n_in,
                              void* d_out, int out_size, void* d_ws, size_t ws_size,
                              hipStream_t stream) {
    const float* edges = (const float*)d_in[0];          // [B,Q,N,C] f32
    const int* query_indices  = (const int*)d_in[1];     // [B,T]
    const int* target_indices = (const int*)d_in[2];     // [B,T]
    const int* col_ids        = (const int*)d_in[3];     // [B,G,S]
    const int* edge_tgt       = (const int*)d_in[4];     // [B,G,S]
    float* out = (float*)d_out;                          // [B,Q,B*G]

    edge_cost_fused_kernel<<<BB * (QQ / QPB), 256, 0, stream>>>(
        edges, query_indices, target_indices, col_ids, edge_tgt, out);
}